// Round 3
// baseline (245.691 us; speedup 1.0000x reference)
//
#include <hip/hip_runtime.h>
#include <hip/hip_bf16.h>

#define N_NODES 50000
#define N_EDGES 1600000
#define HEADS 8
#define HFD 16
#define CH 128      // channels

// fine bucketing: bucket = dst>>5 (32 dst nodes per bucket)
#define NB2 1563            // ceil(50000/32)
#define ECAP2 1280          // per-bucket edge capacity (mean 1024, +8 sigma)
#define PA_T 512
#define PA_CHUNK 3200       // edges per pass-A block
#define PA_PER 7            // 512*7 = 3584 >= 3200
#define PA_BLOCKS 500       // 500*3200 = 1.6M

#define AG_BLOCKS 1568      // 8 * 196 >= NB2, multiple of 8 for XCD swizzle
#define SCHED_CAP 672       // >= ECAP2/2 + 32

typedef __bf16 bf16x8 __attribute__((ext_vector_type(8)));
typedef __bf16 bf16x4 __attribute__((ext_vector_type(4)));
typedef float f32x4 __attribute__((ext_vector_type(4)));

__device__ __forceinline__ float bf_lo(unsigned u) { return __uint_as_float(u << 16); }
__device__ __forceinline__ float bf_hi(unsigned u) { return __uint_as_float(u & 0xffff0000u); }

// ---------------------------------------------------------------------------
// Prep: split W f32 -> bf16 hi/lo; build 16x128 logit tile Veff; zero counts.
// ---------------------------------------------------------------------------
__global__ __launch_bounds__(256) void k_splitw(const float* __restrict__ W,
                                                const float* __restrict__ aL,
                                                const float* __restrict__ aR,
                                                __bf16* __restrict__ Whi,
                                                __bf16* __restrict__ Wlo,
                                                __bf16* __restrict__ Vhi,
                                                __bf16* __restrict__ Vlo,
                                                int* __restrict__ bucket_cnt) {
  int t = blockIdx.x * 256 + threadIdx.x;
  if (t < NB2) bucket_cnt[t] = 0;
  if (t < CH * CH / 4) {
    f32x4 v = ((const f32x4*)W)[t];
    bf16x4 h, l;
#pragma unroll
    for (int i = 0; i < 4; ++i) {
      __bf16 hb = (__bf16)v[i];
      h[i] = hb;
      l[i] = (__bf16)(v[i] - (float)hb);
    }
    ((bf16x4*)Whi)[t] = h;
    ((bf16x4*)Wlo)[t] = l;
  }
  if (t < 16 * CH) {
    int j = t >> 7;          // 0..15: logit row (0..7 left, 8..15 right)
    int k = t & 127;         // input channel
    int h = j & 7;
    const float* a = (j < 8) ? aL : aR;
    float v = 0.f;
#pragma unroll
    for (int c = 0; c < HFD; ++c) v += W[(h * HFD + c) * CH + k] * a[c * HEADS + h];
    __bf16 hb = (__bf16)v;
    Vhi[t] = hb;
    Vlo[t] = (__bf16)(v - (float)hb);
  }
}

// ---------------------------------------------------------------------------
// emb = X @ W^T via split-bf16 MFMA (R0-proven version: 256B-aligned embb
// rows + separate leftp/rightp). C/D: col=lane&15, row=(lane>>4)*4+r.
// ---------------------------------------------------------------------------
__global__ __launch_bounds__(64) void k_emb(const float* __restrict__ X,
                                            const __bf16* __restrict__ Whi,
                                            const __bf16* __restrict__ Wlo,
                                            const __bf16* __restrict__ Vhi,
                                            const __bf16* __restrict__ Vlo,
                                            __bf16* __restrict__ embb,
                                            float* __restrict__ leftp,
                                            float* __restrict__ rightp) {
  int ntile = blockIdx.x;
  int lane = threadIdx.x;
  int c = lane & 15, quad = lane >> 4;
  const float* xp = X + (size_t)(ntile * 16 + c) * CH + quad * 8;
  bf16x8 xh[4], xl[4];
#pragma unroll
  for (int ks = 0; ks < 4; ++ks) {
    float4 x0 = *(const float4*)(xp + ks * 32);
    float4 x1 = *(const float4*)(xp + ks * 32 + 4);
    float xv[8] = {x0.x, x0.y, x0.z, x0.w, x1.x, x1.y, x1.z, x1.w};
#pragma unroll
    for (int j = 0; j < 8; ++j) {
      __bf16 hb = (__bf16)xv[j];
      xh[ks][j] = hb;
      xl[ks][j] = (__bf16)(xv[j] - (float)hb);
    }
  }
#pragma unroll
  for (int h = 0; h < HEADS; ++h) {
    const __bf16* wp = Whi + (size_t)(h * 16 + c) * CH + quad * 8;
    const __bf16* wlp = Wlo + (size_t)(h * 16 + c) * CH + quad * 8;
    f32x4 acc = {0.f, 0.f, 0.f, 0.f};
#pragma unroll
    for (int ks = 0; ks < 4; ++ks) {
      bf16x8 wh = *(const bf16x8*)(wp + ks * 32);
      bf16x8 wl = *(const bf16x8*)(wlp + ks * 32);
      acc = __builtin_amdgcn_mfma_f32_16x16x32_bf16(xl[ks], wh, acc, 0, 0, 0);
      acc = __builtin_amdgcn_mfma_f32_16x16x32_bf16(xh[ks], wl, acc, 0, 0, 0);
      acc = __builtin_amdgcn_mfma_f32_16x16x32_bf16(xh[ks], wh, acc, 0, 0, 0);
    }
#pragma unroll
    for (int r = 0; r < 4; ++r) {
      int node = ntile * 16 + quad * 4 + r;
      embb[(size_t)node * CH + h * HFD + c] = (__bf16)acc[r];
    }
  }
  // logit tile: j<8 -> left head j, j>=8 -> right head j-8
  {
    const __bf16* vp = Vhi + (size_t)c * CH + quad * 8;
    const __bf16* vlp = Vlo + (size_t)c * CH + quad * 8;
    f32x4 acc = {0.f, 0.f, 0.f, 0.f};
#pragma unroll
    for (int ks = 0; ks < 4; ++ks) {
      bf16x8 vh = *(const bf16x8*)(vp + ks * 32);
      bf16x8 vl = *(const bf16x8*)(vlp + ks * 32);
      acc = __builtin_amdgcn_mfma_f32_16x16x32_bf16(xl[ks], vh, acc, 0, 0, 0);
      acc = __builtin_amdgcn_mfma_f32_16x16x32_bf16(xh[ks], vl, acc, 0, 0, 0);
      acc = __builtin_amdgcn_mfma_f32_16x16x32_bf16(xh[ks], vh, acc, 0, 0, 0);
    }
#pragma unroll
    for (int r = 0; r < 4; ++r) {
      int node = ntile * 16 + quad * 4 + r;
      if (c < 8) leftp[node * HEADS + c] = acc[r];
      else rightp[node * HEADS + (c - 8)] = acc[r];
    }
  }
}

// ---------------------------------------------------------------------------
// Pass A: bucket edges by dst>>5 into 1563 fine windows. Packed 4 B edges in
// registers through hist -> 2-level scan -> LDS sort -> run-contiguous global
// writes. p = (dst:16 <<16) | (src:16); bucket = p>>21; dstloc = (p>>16)&31.
// ---------------------------------------------------------------------------
__global__ __launch_bounds__(PA_T) void k_bucket(const int* __restrict__ ei,
                                                 int* __restrict__ bucket_cnt,
                                                 unsigned* __restrict__ ebuf) {
  __shared__ unsigned sp[PA_CHUNK];   // 12.8 KB sorted edges
  __shared__ int hist[NB2 + 1];
  __shared__ int lcur[NB2];
  __shared__ int wbase[NB2];
  __shared__ int scn[PA_T];
  int t = threadIdx.x;
  int base = blockIdx.x * PA_CHUNK;
  for (int i = t; i < NB2; i += PA_T) hist[i] = 0;
  __syncthreads();
  unsigned pk[PA_PER];
#pragma unroll
  for (int i = 0; i < PA_PER; ++i) {
    int e = t + i * PA_T;
    pk[i] = 0xffffffffu;
    if (e < PA_CHUNK) {
      int src = ei[base + e];
      int dst = ei[N_EDGES + base + e];
      pk[i] = ((unsigned)dst << 16) | (unsigned)src;
      atomicAdd(&hist[dst >> 5], 1);
    }
  }
  __syncthreads();
  // 2-level exclusive scan over NB2: per-thread 4-bucket sums + 512 H-S
  int b4 = t * 4;
  int h0 = (b4 < NB2) ? hist[b4] : 0;
  int h1 = (b4 + 1 < NB2) ? hist[b4 + 1] : 0;
  int h2 = (b4 + 2 < NB2) ? hist[b4 + 2] : 0;
  int h3 = (b4 + 3 < NB2) ? hist[b4 + 3] : 0;
  int s4 = h0 + h1 + h2 + h3;
  scn[t] = s4;
  __syncthreads();
  int val = scn[t];
  for (int d = 1; d < PA_T; d <<= 1) {
    int o = (t >= d) ? scn[t - d] : 0;
    __syncthreads();
    val += o;
    scn[t] = val;
    __syncthreads();
  }
  {
    int lst = val - s4;      // exclusive base of this 4-group
    int run[4] = {h0, h1, h2, h3};
#pragma unroll
    for (int j = 0; j < 4; ++j) {
      int b = b4 + j;
      if (b < NB2) {
        lcur[b] = lst;
        int prior = run[j] ? atomicAdd(&bucket_cnt[b], run[j]) : 0;
        wbase[b] = b * ECAP2 + prior - lst;
        lst += run[j];
      }
    }
  }
  __syncthreads();
#pragma unroll
  for (int i = 0; i < PA_PER; ++i) {
    if (pk[i] != 0xffffffffu) {
      int b = pk[i] >> 21;
      int pos = atomicAdd(&lcur[b], 1);
      sp[pos] = pk[i];
    }
  }
  __syncthreads();
  for (int i = t; i < PA_CHUNK; i += PA_T) {
    unsigned p = sp[i];
    int b = p >> 21;
    int slot = wbase[b] + i;
    if (slot < (b + 1) * ECAP2) ebuf[slot] = p;  // capacity guard (~never fires)
  }
}

// ---------------------------------------------------------------------------
// Aggregate, v4: one block per fine bucket (32 dsts, 256 threads, 1563 tasks).
//  * Own-window prologue: reads exactly its ~1024 edges (2 coalesced passes).
//  * TEAM layout: 16 lanes = one dst's 128 channels; head h = (lane&15)>>1 so
//    per-lane dsum is complete locally -> commit = rcp + 2 stores, ZERO
//    shuffles. su/sched reads are 16-lane broadcasts (no bank conflicts).
//  * Pair-schedule: one u32 per 2 edges (base:11|dl:5|first:1|nv2:1) built in
//    the prologue; teams get dst-aligned, pair-balanced contiguous ranges;
//    the main loop is a flat depth-2 pipeline across ALL the team's dsts --
//    no per-dst drain, ~6 VALU decode per pair.
// ---------------------------------------------------------------------------
__global__ __launch_bounds__(256) void k_aggr(const int* __restrict__ bucket_cnt,
                                              const unsigned* __restrict__ ebuf,
                                              const __bf16* __restrict__ embb,
                                              const float* __restrict__ leftp,
                                              const float* __restrict__ rightp,
                                              const float* __restrict__ bias,
                                              float* __restrict__ out) {
  __shared__ unsigned short su[ECAP2];   // 2.5 KB dstloc-sorted src ids
  __shared__ int hist[32];
  __shared__ int pfx[32];
  __shared__ int cur[32];
  __shared__ int poff[32];
  __shared__ int tb[17];
  __shared__ float r_lds[256];
  __shared__ unsigned sched[SCHED_CAP];
  __shared__ int Ptot;

  int T = (blockIdx.x & 7) * 196 + (blockIdx.x >> 3);  // XCD-clustered tasks
  if (T >= NB2) return;
  int t = threadIdx.x;
  int dstbase = T * 32;
  int cnt = bucket_cnt[T];
  if (cnt > ECAP2) cnt = ECAP2;
  const unsigned* wnd = ebuf + (size_t)T * ECAP2;

  if (t < 32) hist[t] = 0;
  {
    int dst = dstbase + (t >> 3);
    r_lds[t] = (dst < N_NODES) ? rightp[dst * HEADS + (t & 7)] : 0.f;
  }
  __syncthreads();
  // pass 1: histogram own window (coalesced)
  for (int e = t; e < cnt; e += 256) atomicAdd(&hist[(wnd[e] >> 16) & 31], 1);
  __syncthreads();
  // 32-entry scans (edges and pairs) in wave 0
  if (t < 64) {
    int hv = (t < 32) ? hist[t] : 0;
    int v = hv;
#pragma unroll
    for (int d = 1; d < 32; d <<= 1) {
      int o = __shfl_up(v, d);
      if ((t & 63) >= d) v += o;
    }
    if (t < 32) { pfx[t] = v - hv; cur[t] = v - hv; }
    int np = (t < 32) ? (hv + 1) >> 1 : 0;
    int pv = np;
#pragma unroll
    for (int d = 1; d < 32; d <<= 1) {
      int o = __shfl_up(pv, d);
      if ((t & 63) >= d) pv += o;
    }
    if (t < 32) poff[t] = pv - np;
    if (t == 31) Ptot = pv;
  }
  __syncthreads();
  int P = Ptot;
  // team boundaries (dst-aligned, pair-balanced): single thread, 32 iters
  if (t == 0) {
    tb[0] = 0;
    int curw = 0;
    if (P > 0) {
      for (int dl = 0; dl < 32; ++dl) {
        int w = (int)((16LL * poff[dl]) / P);
        if (w > 15) w = 15;
        while (curw < w) tb[++curw] = poff[dl];
      }
    }
    while (curw < 16) tb[++curw] = P;
  }
  // build pair schedule: entry = base:11 | dl:5 (<<11) | first (<<16) | nv2 (<<17)
  if (t < 32) {
    int cd = hist[t], basee = pfx[t], po = poff[t];
    int e = 0;
    for (int e2 = 0; e2 < cd; e2 += 2, ++e) {
      unsigned nv2 = (cd - e2 > 1) ? 1u : 0u;
      sched[po + e] = (unsigned)(basee + e2) | ((unsigned)t << 11) |
                      ((e == 0) ? (1u << 16) : 0u) | (nv2 << 17);
    }
  }
  __syncthreads();
  // pass 2: scatter srcs into su sorted by dstloc
  for (int e = t; e < cnt; e += 256) {
    unsigned p = wnd[e];
    int dl = (p >> 16) & 31;
    int pos = atomicAdd(&cur[dl], 1);
    if (pos < ECAP2) su[pos] = (unsigned short)(p & 0xffffu);
  }
  __syncthreads();

  int lane = t & 63;
  int tm = (t >> 6) * 4 + (lane >> 4);  // team 0..15 (one dst at a time)
  int m = lane & 15;                    // channels 8m..8m+7
  int h = m >> 1;                       // head of this slice
  float4 bb0 = ((const float4*)bias)[2 * m];
  float4 bb1 = ((const float4*)bias)[2 * m + 1];

  int pi = tb[tm], pe = tb[tm + 1];
  float acc0 = 0.f, acc1 = 0.f, acc2 = 0.f, acc3 = 0.f;
  float acc4 = 0.f, acc5 = 0.f, acc6 = 0.f, acc7 = 0.f;
  float dsum = 0.f, r = 0.f;
  int prev = -1;

  unsigned eA = 0, eB = 0;
  uint4 uA0, uA1, uB0, uB1;
  float lA0 = 0.f, lA1 = 0.f, lB0 = 0.f, lB1 = 0.f;

#define STAGE(E, U0, U1, L0, L1)                                     \
  {                                                                  \
    E = sched[pi];                                                   \
    int ba = E & 0x7ff;                                              \
    int s0 = su[ba];                                                 \
    int s1 = su[ba + ((E >> 17) & 1)];                               \
    U0 = ((const uint4*)(embb + (size_t)s0 * CH))[m];                \
    U1 = ((const uint4*)(embb + (size_t)s1 * CH))[m];                \
    L0 = leftp[s0 * HEADS + h];                                      \
    L1 = leftp[s1 * HEADS + h];                                      \
  }

#define COMMIT()                                                     \
  {                                                                  \
    float inv = (dsum > 0.f) ? 1.0f / dsum : 0.f;                    \
    float* op = out + (size_t)(dstbase + prev) * CH;                 \
    float4 o0 = {acc0 * inv + bb0.x, acc1 * inv + bb0.y,             \
                 acc2 * inv + bb0.z, acc3 * inv + bb0.w};            \
    float4 o1 = {acc4 * inv + bb1.x, acc5 * inv + bb1.y,             \
                 acc6 * inv + bb1.z, acc7 * inv + bb1.w};            \
    ((float4*)op)[2 * m] = o0;                                       \
    ((float4*)op)[2 * m + 1] = o1;                                   \
  }

#define CONSUME(E, U0, U1, L0, L1)                                   \
  {                                                                  \
    if (E & (1u << 16)) {                                            \
      if (prev >= 0) COMMIT();                                       \
      prev = (E >> 11) & 31;                                         \
      r = r_lds[prev * 8 + h];                                       \
      acc0 = acc1 = acc2 = acc3 = acc4 = acc5 = acc6 = acc7 = 0.f;   \
      dsum = 0.f;                                                    \
    }                                                                \
    float x0 = L0 + r;                                               \
    x0 = (x0 >= 0.f) ? x0 : 0.2f * x0;                               \
    float w0 = __expf(x0);                                           \
    float x1 = L1 + r;                                               \
    x1 = (x1 >= 0.f) ? x1 : 0.2f * x1;                               \
    float w1 = ((E >> 17) & 1) ? __expf(x1) : 0.f;                   \
    dsum += w0 + w1;                                                 \
    acc0 += w0 * bf_lo(U0.x) + w1 * bf_lo(U1.x);                     \
    acc1 += w0 * bf_hi(U0.x) + w1 * bf_hi(U1.x);                     \
    acc2 += w0 * bf_lo(U0.y) + w1 * bf_lo(U1.y);                     \
    acc3 += w0 * bf_hi(U0.y) + w1 * bf_hi(U1.y);                     \
    acc4 += w0 * bf_lo(U0.z) + w1 * bf_lo(U1.z);                     \
    acc5 += w0 * bf_hi(U0.z) + w1 * bf_hi(U1.z);                     \
    acc6 += w0 * bf_lo(U0.w) + w1 * bf_lo(U1.w);                     \
    acc7 += w0 * bf_hi(U0.w) + w1 * bf_hi(U1.w);                     \
  }

  bool vA = pi < pe;
  if (vA) STAGE(eA, uA0, uA1, lA0, lA1);
  pi++;
  bool vB = pi < pe;
  if (vB) STAGE(eB, uB0, uB1, lB0, lB1);
  pi++;
  while (__any(vA)) {
    if (vA) CONSUME(eA, uA0, uA1, lA0, lA1);
    vA = pi < pe;
    if (vA) STAGE(eA, uA0, uA1, lA0, lA1);
    pi++;
    if (!__any(vB)) break;
    if (vB) CONSUME(eB, uB0, uB1, lB0, lB1);
    vB = pi < pe;
    if (vB) STAGE(eB, uB0, uB1, lB0, lB1);
    pi++;
  }
  if (prev >= 0) COMMIT();
#undef STAGE
#undef COMMIT
#undef CONSUME

  // dsts with no edges: out = bias (block-wide float4 fill)
  for (int z = t; z < 32 * 32; z += 256) {
    int dl = z >> 5, c4 = z & 31;
    if (hist[dl] == 0) {
      int dst = dstbase + dl;
      if (dst < N_NODES)
        ((float4*)(out + (size_t)dst * CH))[c4] = ((const float4*)bias)[c4];
    }
  }
}

extern "C" void kernel_launch(void* const* d_in, const int* in_sizes, int n_in,
                              void* d_out, int out_size, void* d_ws, size_t ws_size,
                              hipStream_t stream) {
  const float* X = (const float*)d_in[0];
  const int* ei = (const int*)d_in[1];
  const float* W = (const float*)d_in[2];
  const float* al = (const float*)d_in[3];
  const float* ar = (const float*)d_in[4];
  const float* bias = (const float*)d_in[5];
  float* out = (float*)d_out;

  // workspace layout (~25.8 MB); all segments 16 B-aligned
  unsigned* ebuf = (unsigned*)d_ws;                         // NB2*ECAP2 u32 (8.0 MB)
  __bf16* embb = (__bf16*)(ebuf + (size_t)NB2 * ECAP2);     // N*128 bf16 (12.8 MB)
  __bf16* Whi = embb + (size_t)N_NODES * CH;                // 16K bf16
  __bf16* Wlo = Whi + CH * CH;                              // 16K bf16
  __bf16* Vhi = Wlo + CH * CH;                              // 2K bf16
  __bf16* Vlo = Vhi + 16 * CH;                              // 2K bf16
  float* leftp = (float*)(Vlo + 16 * CH);                   // N*8 f32 (1.6 MB, L2-resident)
  float* rightp = leftp + (size_t)N_NODES * HEADS;          // N*8 f32
  int* bucket_cnt = (int*)(rightp + (size_t)N_NODES * HEADS);  // NB2 int

  k_splitw<<<16, 256, 0, stream>>>(W, al, ar, Whi, Wlo, Vhi, Vlo, bucket_cnt);
  k_bucket<<<PA_BLOCKS, PA_T, 0, stream>>>(ei, bucket_cnt, ebuf);
  k_emb<<<N_NODES / 16, 64, 0, stream>>>(X, Whi, Wlo, Vhi, Vlo, embb, leftp, rightp);
  k_aggr<<<AG_BLOCKS, 256, 0, stream>>>(bucket_cnt, ebuf, embb, leftp, rightp, bias, out);
}

// Round 5
// 203.725 us; speedup vs baseline: 1.2060x; 1.2060x over previous
//
#include <hip/hip_runtime.h>
#include <hip/hip_bf16.h>

#define N_NODES 50000
#define N_EDGES 1600000
#define HEADS 8
#define HFD 16
#define CH 128      // channels

// bucketing: bucket = dst>>7 (128 dst nodes per bucket)
#define PART 128
#define NB 391              // ceil(50000/128)
#define BCAP 5120           // edge capacity per bucket (mean 4096, +16 sigma)
#define PA_T 512
#define PA_CHUNK 3200       // edges per pass-A block
#define PA_PER 7            // 512*7 = 3584 >= 3200
#define PA_BLOCKS 500       // 500*3200 = 1.6M

// k_aggr geometry: one block per QUARTER bucket (32 dsts), 256 threads
#define QPART 32
#define QCAP 1536           // per-quarter edge capacity (mean 1024, +16 sigma)
#define AG_TASKS (NB * 4)   // 1564
#define AG_BLOCKS 1568      // 8 * 196, multiple of 8 for XCD swizzle

typedef __bf16 bf16x8 __attribute__((ext_vector_type(8)));
typedef __bf16 bf16x4 __attribute__((ext_vector_type(4)));
typedef float f32x4 __attribute__((ext_vector_type(4)));
typedef float f32x2 __attribute__((ext_vector_type(2)));

__device__ __forceinline__ float bf_lo(unsigned u) { return __uint_as_float(u << 16); }
__device__ __forceinline__ float bf_hi(unsigned u) { return __uint_as_float(u & 0xffff0000u); }

// ---------------------------------------------------------------------------
// Prep kernel: (a) split W f32 -> bf16 hi/lo; (b) build the 16x128 effective
// logit tile Veff; (c) zero bucket_cnt.
// ---------------------------------------------------------------------------
__global__ __launch_bounds__(256) void k_splitw(const float* __restrict__ W,
                                                const float* __restrict__ aL,
                                                const float* __restrict__ aR,
                                                __bf16* __restrict__ Whi,
                                                __bf16* __restrict__ Wlo,
                                                __bf16* __restrict__ Vhi,
                                                __bf16* __restrict__ Vlo,
                                                int* __restrict__ bucket_cnt) {
  int t = blockIdx.x * 256 + threadIdx.x;
  if (t < NB) bucket_cnt[t] = 0;
  if (t < CH * CH / 4) {
    f32x4 v = ((const f32x4*)W)[t];
    bf16x4 h, l;
#pragma unroll
    for (int i = 0; i < 4; ++i) {
      __bf16 hb = (__bf16)v[i];
      h[i] = hb;
      l[i] = (__bf16)(v[i] - (float)hb);
    }
    ((bf16x4*)Whi)[t] = h;
    ((bf16x4*)Wlo)[t] = l;
  }
  if (t < 16 * CH) {
    int j = t >> 7;          // 0..15: logit row (0..7 left, 8..15 right)
    int k = t & 127;         // input channel
    int h = j & 7;
    const float* a = (j < 8) ? aL : aR;
    float v = 0.f;
#pragma unroll
    for (int c = 0; c < HFD; ++c) v += W[(h * HFD + c) * CH + k] * a[c * HEADS + h];
    __bf16 hb = (__bf16)v;
    Vhi[t] = hb;
    Vlo[t] = (__bf16)(v - (float)hb);
  }
}

// ---------------------------------------------------------------------------
// emb = X @ W^T via split-bf16 MFMA (R1-proven version: 256B-aligned embb
// rows + separate leftp/rightp). C/D: col=lane&15, row=(lane>>4)*4+r.
// ---------------------------------------------------------------------------
__global__ __launch_bounds__(64) void k_emb(const float* __restrict__ X,
                                            const __bf16* __restrict__ Whi,
                                            const __bf16* __restrict__ Wlo,
                                            const __bf16* __restrict__ Vhi,
                                            const __bf16* __restrict__ Vlo,
                                            __bf16* __restrict__ embb,
                                            float* __restrict__ leftp,
                                            float* __restrict__ rightp) {
  int ntile = blockIdx.x;
  int lane = threadIdx.x;
  int c = lane & 15, quad = lane >> 4;
  const float* xp = X + (size_t)(ntile * 16 + c) * CH + quad * 8;
  bf16x8 xh[4], xl[4];
#pragma unroll
  for (int ks = 0; ks < 4; ++ks) {
    float4 x0 = *(const float4*)(xp + ks * 32);
    float4 x1 = *(const float4*)(xp + ks * 32 + 4);
    float xv[8] = {x0.x, x0.y, x0.z, x0.w, x1.x, x1.y, x1.z, x1.w};
#pragma unroll
    for (int j = 0; j < 8; ++j) {
      __bf16 hb = (__bf16)xv[j];
      xh[ks][j] = hb;
      xl[ks][j] = (__bf16)(xv[j] - (float)hb);
    }
  }
#pragma unroll
  for (int h = 0; h < HEADS; ++h) {
    const __bf16* wp = Whi + (size_t)(h * 16 + c) * CH + quad * 8;
    const __bf16* wlp = Wlo + (size_t)(h * 16 + c) * CH + quad * 8;
    f32x4 acc = {0.f, 0.f, 0.f, 0.f};
#pragma unroll
    for (int ks = 0; ks < 4; ++ks) {
      bf16x8 wh = *(const bf16x8*)(wp + ks * 32);
      bf16x8 wl = *(const bf16x8*)(wlp + ks * 32);
      acc = __builtin_amdgcn_mfma_f32_16x16x32_bf16(xl[ks], wh, acc, 0, 0, 0);
      acc = __builtin_amdgcn_mfma_f32_16x16x32_bf16(xh[ks], wl, acc, 0, 0, 0);
      acc = __builtin_amdgcn_mfma_f32_16x16x32_bf16(xh[ks], wh, acc, 0, 0, 0);
    }
#pragma unroll
    for (int r = 0; r < 4; ++r) {
      int node = ntile * 16 + quad * 4 + r;
      embb[(size_t)node * CH + h * HFD + c] = (__bf16)acc[r];
    }
  }
  // logit tile: j<8 -> left head j, j>=8 -> right head j-8
  {
    const __bf16* vp = Vhi + (size_t)c * CH + quad * 8;
    const __bf16* vlp = Vlo + (size_t)c * CH + quad * 8;
    f32x4 acc = {0.f, 0.f, 0.f, 0.f};
#pragma unroll
    for (int ks = 0; ks < 4; ++ks) {
      bf16x8 vh = *(const bf16x8*)(vp + ks * 32);
      bf16x8 vl = *(const bf16x8*)(vlp + ks * 32);
      acc = __builtin_amdgcn_mfma_f32_16x16x32_bf16(xl[ks], vh, acc, 0, 0, 0);
      acc = __builtin_amdgcn_mfma_f32_16x16x32_bf16(xh[ks], vl, acc, 0, 0, 0);
      acc = __builtin_amdgcn_mfma_f32_16x16x32_bf16(xh[ks], vh, acc, 0, 0, 0);
    }
#pragma unroll
    for (int r = 0; r < 4; ++r) {
      int node = ntile * 16 + quad * 4 + r;
      if (c < 8) leftp[node * HEADS + c] = acc[r];
      else rightp[node * HEADS + (c - 8)] = acc[r];
    }
  }
}

// ---------------------------------------------------------------------------
// Pass A: bucket edges by dst>>7. Identical to the proven R1 version except
// the 18-barrier Hillis-Steele scan is replaced by a 2-barrier wave-shuffle
// scan (64-lane shfl scan + 8-partial scan in wave 0).
// ---------------------------------------------------------------------------
__global__ __launch_bounds__(PA_T) void k_bucket(const int* __restrict__ ei,
                                                 int* __restrict__ bucket_cnt,
                                                 unsigned* __restrict__ ebuf) {
  __shared__ unsigned sp[PA_CHUNK];   // 12.8 KB sorted edges
  __shared__ int hist[NB];
  __shared__ int lcur[NB];
  __shared__ int wbase[NB];
  __shared__ int wpart[8];
  int t = threadIdx.x;
  int base = blockIdx.x * PA_CHUNK;
  for (int i = t; i < NB; i += PA_T) hist[i] = 0;
  __syncthreads();
  unsigned pk[PA_PER];
#pragma unroll
  for (int i = 0; i < PA_PER; ++i) {
    int e = t + i * PA_T;
    pk[i] = 0xffffffffu;
    if (e < PA_CHUNK) {
      int src = ei[base + e];
      int dst = ei[N_EDGES + base + e];
      pk[i] = ((unsigned)(dst >> 7) << 23) | ((unsigned)(dst & 127) << 16) |
              (unsigned)src;
      atomicAdd(&hist[dst >> 7], 1);
    }
  }
  __syncthreads();
  // inclusive scan over 512 (one bucket per thread): wave shfl scan + partials
  int hv = (t < NB) ? hist[t] : 0;
  int lane = t & 63, wid = t >> 6;
  int v = hv;
#pragma unroll
  for (int d = 1; d < 64; d <<= 1) {
    int o = __shfl_up(v, d);
    if (lane >= d) v += o;
  }
  if (lane == 63) wpart[wid] = v;
  __syncthreads();
  if (t < 8) {
    int pv = wpart[t];
#pragma unroll
    for (int d = 1; d < 8; d <<= 1) {
      int o = __shfl_up(pv, d);
      if (t >= d) pv += o;
    }
    wpart[t] = pv;
  }
  __syncthreads();
  int val = v + ((wid > 0) ? wpart[wid - 1] : 0);
  if (t < NB) {
    int lstart = val - hv;
    lcur[t] = lstart;
    int prior = hv ? atomicAdd(&bucket_cnt[t], hv) : 0;
    wbase[t] = t * BCAP + prior - lstart;
  }
  __syncthreads();
#pragma unroll
  for (int i = 0; i < PA_PER; ++i) {
    if (pk[i] != 0xffffffffu) {
      int b = pk[i] >> 23;
      int pos = atomicAdd(&lcur[b], 1);
      sp[pos] = pk[i];
    }
  }
  __syncthreads();
  for (int i = t; i < PA_CHUNK; i += PA_T) {
    unsigned p = sp[i];
    int b = p >> 23;
    int slot = wbase[b] + i;
    if (slot < (b + 1) * BCAP) ebuf[slot] = p;  // capacity guard (never fires)
  }
}

// ---------------------------------------------------------------------------
// Fused CSR-sort + pull-aggregate: R1-proven structure (quarter-bucket, 256
// threads, uniform per-wave dst loop) with two surgical edits:
//  * acc packed as float2[4] -> v_pk_fma_f32 halves the accumulate VALU.
//  * depth-3 A/B/C pipeline (12 edges in flight/wave vs 8); consumption
//    order (and therefore numerics) unchanged.
// ---------------------------------------------------------------------------
__global__ __launch_bounds__(256) void k_aggr(const int* __restrict__ bucket_cnt,
                                              const unsigned* __restrict__ ebuf,
                                              const __bf16* __restrict__ embb,
                                              const float* __restrict__ leftp,
                                              const float* __restrict__ rightp,
                                              const float* __restrict__ bias,
                                              float* __restrict__ out) {
  __shared__ unsigned short su[QCAP];  // 3 KB: dstloc-sorted src ids (this quarter)
  __shared__ int hist[QPART];
  __shared__ int pfx[QPART];
  __shared__ int cur[QPART];
  // XCD-clustered task mapping: tasks T, T+1.. on the same XCD (xcd = bid%8)
  int T = (blockIdx.x & 7) * (AG_BLOCKS / 8) + (blockIdx.x >> 3);
  if (T >= AG_TASKS) return;
  int b = T >> 2;           // bucket
  int q = T & 3;            // quarter within bucket (dstloc 32q..32q+31)
  int t = threadIdx.x;
  int cnt = bucket_cnt[b];
  if (cnt > BCAP) cnt = BCAP;
  int ebase = b * BCAP;
  if (t < QPART) hist[t] = 0;
  __syncthreads();
  // pass 1: histogram this quarter's dstlocs (uint4 reads; tail over-read
  // stays inside the ebuf bucket window -> safe)
  for (int e4 = t * 4; e4 < cnt; e4 += 1024) {
    uint4 pp = *(const uint4*)(ebuf + ebase + e4);
    unsigned pj[4] = {pp.x, pp.y, pp.z, pp.w};
#pragma unroll
    for (int j = 0; j < 4; ++j) {
      if (e4 + j < cnt) {
        int dl = (pj[j] >> 16) & 127;
        if ((dl >> 5) == q) atomicAdd(&hist[dl & 31], 1);
      }
    }
  }
  __syncthreads();
  // 32-entry exclusive scan via wave-0 shuffles
  if (t < 64) {
    int v = (t < QPART) ? hist[t] : 0;
#pragma unroll
    for (int d = 1; d < QPART; d <<= 1) {
      int o = __shfl_up(v, d);
      if (t >= d) v += o;
    }
    if (t < QPART) {
      int ex = v - hist[t];
      pfx[t] = ex;
      cur[t] = ex;
    }
  }
  __syncthreads();
  // pass 2: scatter this quarter's srcs into su, sorted by dstloc
  for (int e4 = t * 4; e4 < cnt; e4 += 1024) {
    uint4 pp = *(const uint4*)(ebuf + ebase + e4);
    unsigned pj[4] = {pp.x, pp.y, pp.z, pp.w};
#pragma unroll
    for (int j = 0; j < 4; ++j) {
      if (e4 + j < cnt) {
        unsigned p = pj[j];
        int dl = (p >> 16) & 127;
        if ((dl >> 5) == q) {
          int pos = atomicAdd(&cur[dl & 31], 1);
          if (pos < QCAP) su[pos] = (unsigned short)(p & 0xffffu);
        }
      }
    }
  }
  __syncthreads();

  int wv = t >> 6;          // wave 0..3, each owns 8 dsts
  int lane = t & 63;
  int g = lane >> 4;        // edge group 0..3
  int m = lane & 15;        // 16 B slice: channels 8m..8m+7
  int h = m >> 1;           // head of this slice
#pragma unroll 1
  for (int k = 0; k < 8; ++k) {
    int dl = wv * 8 + k;    // 0..31 within quarter
    int dst = b * PART + q * QPART + dl;
    bool valid = dst < N_NODES;
    int beg = pfx[dl];
    int cd = hist[dl];
    if (beg + cd > QCAP) cd = QCAP - beg;  // paranoia (never fires)
    float r = valid ? rightp[dst * HEADS + h] : 0.f;
    f32x2 acc2[4];
    acc2[0] = (f32x2){0.f, 0.f};
    acc2[1] = (f32x2){0.f, 0.f};
    acc2[2] = (f32x2){0.f, 0.f};
    acc2[3] = (f32x2){0.f, 0.f};
    float dsum = 0.f;
    if (cd > 0) {
      int sA0, sA1, sB0, sB1, sC0, sC1;
      uint4 uA0, uA1, uB0, uB1, uC0, uC1;
      float lA0, lA1, lB0, lB1, lC0, lC1;
#define STAGE(E0, s0, s1, u0, u1, l0, l1)                          \
      {                                                            \
        int i0 = (E0) + g, i1 = (E0) + 4 + g;                      \
        s0 = su[beg + ((i0 < cd) ? i0 : 0)];                       \
        s1 = su[beg + ((i1 < cd) ? i1 : 0)];                       \
        u0 = ((const uint4*)(embb + (size_t)s0 * CH))[m];          \
        u1 = ((const uint4*)(embb + (size_t)s1 * CH))[m];          \
        l0 = leftp[s0 * HEADS + h];                                \
        l1 = leftp[s1 * HEADS + h];                                \
      }
#define CONSUME(E0, u0, u1, l0, l1)                                \
      {                                                            \
        bool a0 = (E0) + g < cd, a1 = (E0) + 4 + g < cd;           \
        float x0 = l0 + r;                                         \
        x0 = (x0 >= 0.f) ? x0 : 0.2f * x0;                         \
        float w0 = a0 ? __expf(x0) : 0.f;                          \
        float x1 = l1 + r;                                         \
        x1 = (x1 >= 0.f) ? x1 : 0.2f * x1;                         \
        float w1 = a1 ? __expf(x1) : 0.f;                          \
        dsum += w0 + w1;                                           \
        f32x2 wv0 = {w0, w0}, wv1 = {w1, w1};                      \
        acc2[0] += wv0 * (f32x2){bf_lo(u0.x), bf_hi(u0.x)}         \
                 + wv1 * (f32x2){bf_lo(u1.x), bf_hi(u1.x)};        \
        acc2[1] += wv0 * (f32x2){bf_lo(u0.y), bf_hi(u0.y)}         \
                 + wv1 * (f32x2){bf_lo(u1.y), bf_hi(u1.y)};        \
        acc2[2] += wv0 * (f32x2){bf_lo(u0.z), bf_hi(u0.z)}         \
                 + wv1 * (f32x2){bf_lo(u1.z), bf_hi(u1.z)};        \
        acc2[3] += wv0 * (f32x2){bf_lo(u0.w), bf_hi(u0.w)}         \
                 + wv1 * (f32x2){bf_lo(u1.w), bf_hi(u1.w)};        \
      }
      STAGE(0, sA0, sA1, uA0, uA1, lA0, lA1);
      if (8 < cd) STAGE(8, sB0, sB1, uB0, uB1, lB0, lB1);
      int e0 = 0;
      while (true) {
        if (e0 + 16 < cd) STAGE(e0 + 16, sC0, sC1, uC0, uC1, lC0, lC1);
        CONSUME(e0, uA0, uA1, lA0, lA1);
        e0 += 8;
        if (e0 >= cd) break;
        if (e0 + 16 < cd) STAGE(e0 + 16, sA0, sA1, uA0, uA1, lA0, lA1);
        CONSUME(e0, uB0, uB1, lB0, lB1);
        e0 += 8;
        if (e0 >= cd) break;
        if (e0 + 16 < cd) STAGE(e0 + 16, sB0, sB1, uB0, uB1, lB0, lB1);
        CONSUME(e0, uC0, uC1, lC0, lC1);
        e0 += 8;
        if (e0 >= cd) break;
      }
#undef STAGE
#undef CONSUME
    }
    // reduce over the 4 edge groups (lane bits 4,5)
    float a0 = acc2[0].x, a1 = acc2[0].y, a2 = acc2[1].x, a3 = acc2[1].y;
    float a4 = acc2[2].x, a5 = acc2[2].y, a6 = acc2[3].x, a7 = acc2[3].y;
#pragma unroll
    for (int mask = 16; mask <= 32; mask <<= 1) {
      dsum += __shfl_xor(dsum, mask);
      a0 += __shfl_xor(a0, mask);
      a1 += __shfl_xor(a1, mask);
      a2 += __shfl_xor(a2, mask);
      a3 += __shfl_xor(a3, mask);
      a4 += __shfl_xor(a4, mask);
      a5 += __shfl_xor(a5, mask);
      a6 += __shfl_xor(a6, mask);
      a7 += __shfl_xor(a7, mask);
    }
    if (g == 0 && valid) {
      float inv = (dsum > 0.f) ? 1.0f / dsum : 0.f;
      float4 b0 = ((const float4*)bias)[2 * m];
      float4 b1 = ((const float4*)bias)[2 * m + 1];
      float4 o0 = {a0 * inv + b0.x, a1 * inv + b0.y,
                   a2 * inv + b0.z, a3 * inv + b0.w};
      float4 o1 = {a4 * inv + b1.x, a5 * inv + b1.y,
                   a6 * inv + b1.z, a7 * inv + b1.w};
      ((float4*)(out + (size_t)dst * CH))[2 * m] = o0;
      ((float4*)(out + (size_t)dst * CH))[2 * m + 1] = o1;
    }
  }
}

extern "C" void kernel_launch(void* const* d_in, const int* in_sizes, int n_in,
                              void* d_out, int out_size, void* d_ws, size_t ws_size,
                              hipStream_t stream) {
  const float* X = (const float*)d_in[0];
  const int* ei = (const int*)d_in[1];
  const float* W = (const float*)d_in[2];
  const float* al = (const float*)d_in[3];
  const float* ar = (const float*)d_in[4];
  const float* bias = (const float*)d_in[5];
  float* out = (float*)d_out;

  // workspace layout (~22.6 MB); all segments 16 B-aligned
  unsigned* ebuf = (unsigned*)d_ws;                       // NB*BCAP u32 (8.0 MB)
  __bf16* embb = (__bf16*)(ebuf + (size_t)NB * BCAP);     // N*128 bf16 (12.8 MB)
  __bf16* Whi = embb + (size_t)N_NODES * CH;              // 16K bf16
  __bf16* Wlo = Whi + CH * CH;                            // 16K bf16
  __bf16* Vhi = Wlo + CH * CH;                            // 2K bf16
  __bf16* Vlo = Vhi + 16 * CH;                            // 2K bf16
  float* leftp = (float*)(Vlo + 16 * CH);                 // N*8 f32
  float* rightp = leftp + (size_t)N_NODES * HEADS;        // N*8 f32
  int* bucket_cnt = (int*)(rightp + (size_t)N_NODES * HEADS);  // NB int

  k_splitw<<<16, 256, 0, stream>>>(W, al, ar, Whi, Wlo, Vhi, Vlo, bucket_cnt);
  k_bucket<<<PA_BLOCKS, PA_T, 0, stream>>>(ei, bucket_cnt, ebuf);
  k_emb<<<N_NODES / 16, 64, 0, stream>>>(X, Whi, Wlo, Vhi, Vlo, embb, leftp, rightp);
  k_aggr<<<AG_BLOCKS, 256, 0, stream>>>(bucket_cnt, ebuf, embb, leftp, rightp, bias, out);
}